// Round 3
// baseline (621.457 us; speedup 1.0000x reference)
//
#include <hip/hip_runtime.h>
#include <math.h>

#define N 1024
#define NN (N*N)
#define NE 32768

// ---------------- workspace layout (in floats) ----------------
#define OFF_A0   ((size_t)0)                       // 2 matrices
#define OFF_A1   ((size_t)(2*NN))                  // 3 matrices (contiguous with A0)
#define OFF_M0   ((size_t)(5*NN))
#define OFF_M1   ((size_t)(6*NN))
#define OFF_BT   ((size_t)(7*NN))
#define OFF_H1   ((size_t)(8*NN))                  // 16*512*512 = 4*NN
#define OFF_H2   ((size_t)(12*NN))                 // 4*257*257 = 264196
#define OFF_H3   (OFF_H2 + 264196)                 // 16*514*514 = 4227136
#define OFF_D0   (OFF_H3 + 4227136)
#define OFF_F0   (OFF_D0 + 1024)
#define OFF_D1   (OFF_F0 + 1024)
#define OFF_F1   (OFF_D1 + 1024)
#define OFF_D2   (OFF_F1 + 1024)
#define OFF_F2   (OFF_D2 + 1024)
#define OFF_XW1  (OFF_F2 + 1024)                   // 1024*64
#define OFF_HB   (OFF_XW1 + 65536)                 // 1024*64
#define OFF_HW2  (OFF_HB + 65536)                  // 1024*32

// ---------------- edge scatter (all 5 edge sets, one launch) ----------------
__global__ void k_scatter5(const int* __restrict__ e0, const int* __restrict__ e1,
                           const int* __restrict__ e2, const int* __restrict__ e3,
                           const int* __restrict__ e4, float* __restrict__ A) {
  int g = blockIdx.x * 256 + threadIdx.x;
  int seg = g >> 15;          // 32768 edges per segment
  int k = g & 32767;
  const int* e = (seg == 0) ? e0 : (seg == 1) ? e1 : (seg == 2) ? e2 : (seg == 3) ? e3 : e4;
  atomicAdd(&A[(size_t)seg * NN + (size_t)e[k] * N + e[NE + k]], 1.0f);
}

// ---------------- conv1 (pad=1) + relu + maxpool2 : LxNxN -> 16x512x512 (LDS staged) ----------------
template<int L>
__global__ __launch_bounds__(256) void k_conv1_pool(const float* __restrict__ A,
    const float* __restrict__ W, const float* __restrict__ Bn, float* __restrict__ out) {
  __shared__ float sIn[L][34][35];
  __shared__ float sW[16 * L * 9];
  __shared__ float sB[16];
  int tid = threadIdx.y * 16 + threadIdx.x;
  for (int i = tid; i < 16 * L * 9; i += 256) sW[i] = W[i];
  if (tid < 16) sB[tid] = Bn[tid];
  const int x0 = blockIdx.x * 32 - 1;
  const int y0 = blockIdx.y * 32 - 1;
  for (int idx = tid; idx < L * 34 * 34; idx += 256) {
    int l = idx / (34 * 34);
    int rem = idx - l * 34 * 34;
    int r = rem / 34, c = rem - r * 34;
    int iy = y0 + r, ix = x0 + c;
    sIn[l][r][c] = (iy >= 0 && iy < N && ix >= 0 && ix < N) ? A[(size_t)l * NN + (size_t)iy * N + ix] : 0.f;
  }
  __syncthreads();
  const int tx = threadIdx.x, ty = threadIdx.y;
  float p[L][4][4];
  #pragma unroll
  for (int l = 0; l < L; ++l)
    #pragma unroll
    for (int r = 0; r < 4; ++r)
      #pragma unroll
      for (int c = 0; c < 4; ++c)
        p[l][r][c] = sIn[l][2 * ty + r][2 * tx + c];
  const int ox = blockIdx.x * 16 + tx;
  const int oy = blockIdx.y * 16 + ty;
  for (int oc = 0; oc < 16; ++oc) {
    float wr[L * 9];
    #pragma unroll
    for (int t = 0; t < L * 9; ++t) wr[t] = sW[oc * L * 9 + t];
    float m = -1e30f;
    #pragma unroll
    for (int dy = 0; dy < 2; ++dy)
      #pragma unroll
      for (int dx = 0; dx < 2; ++dx) {
        float s = 0.f;
        #pragma unroll
        for (int l = 0; l < L; ++l)
          #pragma unroll
          for (int ky = 0; ky < 3; ++ky)
            #pragma unroll
            for (int kx = 0; kx < 3; ++kx)
              s = fmaf(p[l][dy + ky][dx + kx], wr[l * 9 + ky * 3 + kx], s);
        m = fmaxf(m, s);
      }
    out[(size_t)oc * 512 * 512 + (size_t)oy * 512 + ox] = fmaxf(m + sB[oc], 0.f);
  }
}

// ---------------- conv2 (pad=2) + relu + maxpool2 : 16x512x512 -> 4x257x257 (LDS staged) ----------------
__global__ __launch_bounds__(256) void k_conv2_pool(const float* __restrict__ in,
    const float* __restrict__ W, const float* __restrict__ Bn, float* __restrict__ out) {
  __shared__ float sIn[36][37];
  __shared__ float sW[4 * 16 * 9];
  __shared__ float sB[4];
  int tid = threadIdx.y * 16 + threadIdx.x;
  for (int i = tid; i < 4 * 16 * 9; i += 256) sW[i] = W[i];
  if (tid < 4) sB[tid] = Bn[tid];
  const int x0 = blockIdx.x * 32 - 2;
  const int y0 = blockIdx.y * 32 - 2;
  const int tx = threadIdx.x, ty = threadIdx.y;
  float acc[4][2][2];
  #pragma unroll
  for (int oc = 0; oc < 4; ++oc)
    #pragma unroll
    for (int dy = 0; dy < 2; ++dy)
      #pragma unroll
      for (int dx = 0; dx < 2; ++dx) acc[oc][dy][dx] = 0.f;
  for (int ic = 0; ic < 16; ++ic) {
    __syncthreads();
    for (int idx = tid; idx < 36 * 36; idx += 256) {
      int r = idx / 36, c = idx - r * 36;
      int iy = y0 + r, ix = x0 + c;
      sIn[r][c] = (iy >= 0 && iy < 512 && ix >= 0 && ix < 512) ? in[(size_t)ic * 512 * 512 + (size_t)iy * 512 + ix] : 0.f;
    }
    __syncthreads();
    float p[4][4];
    #pragma unroll
    for (int r = 0; r < 4; ++r)
      #pragma unroll
      for (int c = 0; c < 4; ++c) p[r][c] = sIn[2 * ty + r][2 * tx + c];
    #pragma unroll
    for (int oc = 0; oc < 4; ++oc)
      #pragma unroll
      for (int ky = 0; ky < 3; ++ky)
        #pragma unroll
        for (int kx = 0; kx < 3; ++kx) {
          float w = sW[oc * 144 + ic * 9 + ky * 3 + kx];
          #pragma unroll
          for (int dy = 0; dy < 2; ++dy)
            #pragma unroll
            for (int dx = 0; dx < 2; ++dx)
              acc[oc][dy][dx] = fmaf(p[dy + ky][dx + kx], w, acc[oc][dy][dx]);
        }
  }
  const int ox = blockIdx.x * 16 + tx;
  const int oy = blockIdx.y * 16 + ty;
  if (ox < 257 && oy < 257) {
    #pragma unroll
    for (int oc = 0; oc < 4; ++oc) {
      float m = fmaxf(fmaxf(acc[oc][0][0], acc[oc][0][1]), fmaxf(acc[oc][1][0], acc[oc][1][1]));
      out[(size_t)oc * 257 * 257 + (size_t)oy * 257 + ox] = fmaxf(m + sB[oc], 0.f);
    }
  }
}

// ---------------- tconv1 (k=2,s=2) + relu : 4x257x257 -> 16x514x514 (flipped weights) ----------------
__global__ __launch_bounds__(256) void k_tconv1(const float* __restrict__ in,
    const float* __restrict__ W, const float* __restrict__ Bn, float* __restrict__ out) {
  __shared__ float sW[16 * 4 * 4];
  __shared__ float sB[16];
  int tid = threadIdx.y * 16 + threadIdx.x;
  for (int i = tid; i < 256; i += 256) sW[i] = W[i];
  if (tid < 16) sB[tid] = Bn[tid];
  __syncthreads();
  int n = blockIdx.x * 16 + threadIdx.x;
  int m = blockIdx.y * 16 + threadIdx.y;
  if (n >= 257 || m >= 257) return;
  float v[4];
  #pragma unroll
  for (int c = 0; c < 4; ++c) v[c] = in[(size_t)c * 257 * 257 + (size_t)m * 257 + n];
  for (int oc = 0; oc < 16; ++oc) {
    #pragma unroll
    for (int dy = 0; dy < 2; ++dy)
      #pragma unroll
      for (int dx = 0; dx < 2; ++dx) {
        float s = sB[oc];
        #pragma unroll
        for (int c = 0; c < 4; ++c)
          s = fmaf(v[c], sW[oc * 16 + c * 4 + (1 - dy) * 2 + (1 - dx)], s);
        out[(size_t)oc * 514 * 514 + (size_t)(2 * m + dy) * 514 + (2 * n + dx)] = fmaxf(s, 0.f);
      }
  }
}

// ---------------- tconv2 (k=2,s=2) + sigmoid, crop to NxN, attended = A*att in-place ----------------
template<int L>
__global__ __launch_bounds__(256) void k_tconv2_sig(const float* __restrict__ h3,
    const float* __restrict__ W, const float* __restrict__ Bn, float* __restrict__ A) {
  __shared__ float sW[L * 16 * 4];
  __shared__ float sB[L];
  int tid = threadIdx.y * 16 + threadIdx.x;
  for (int i = tid; i < L * 64; i += 256) sW[i] = W[i];
  if (tid < L) sB[tid] = Bn[tid];
  __syncthreads();
  int n = blockIdx.x * 16 + threadIdx.x;   // 0..511
  int m = blockIdx.y * 16 + threadIdx.y;   // 0..511
  float v[16];
  #pragma unroll
  for (int c = 0; c < 16; ++c) v[c] = h3[(size_t)c * 514 * 514 + (size_t)m * 514 + n];
  #pragma unroll
  for (int l = 0; l < L; ++l) {
    #pragma unroll
    for (int dy = 0; dy < 2; ++dy)
      #pragma unroll
      for (int dx = 0; dx < 2; ++dx) {
        float s = sB[l];
        #pragma unroll
        for (int c = 0; c < 16; ++c)
          s = fmaf(v[c], sW[l * 64 + c * 4 + (1 - dy) * 2 + (1 - dx)], s);
        float sg = 1.f / (1.f + expf(-s));
        size_t idx = (size_t)l * NN + (size_t)(2 * m + dy) * N + (2 * n + dx);
        A[idx] *= sg;
      }
  }
}

// ---------------- deg: row-sum (+self-loop flag) -> dinv, dflag ----------------
__global__ __launch_bounds__(256) void k_deg(const float* __restrict__ B,
    float* __restrict__ dinv, float* __restrict__ dflag) {
  const int row = blockIdx.x;
  const float4* r4 = (const float4*)(B + (size_t)row * N);
  float4 v = r4[threadIdx.x];
  float s = v.x + v.y + v.z + v.w;
  #pragma unroll
  for (int o = 32; o > 0; o >>= 1) s += __shfl_down(s, o, 64);
  __shared__ float red[4];
  if ((threadIdx.x & 63) == 0) red[threadIdx.x >> 6] = s;
  __syncthreads();
  if (threadIdx.x == 0) {
    float tot = red[0] + red[1] + red[2] + red[3];
    float d = B[(size_t)row * N + row];
    float fl = (d == 0.0f) ? 1.0f : 0.0f;
    float deg = tot + fl;
    dinv[row] = (deg > 0.0f) ? (1.0f / sqrtf(deg)) : 0.0f;
    dflag[row] = fl;
  }
}

// ---------------- split-K matmul with fused left-normalization ----------------
// C += [D^-1/2 (A + flag*I) D^-1/2] @ B over K-range [kz*256, kz*256+256)
__global__ __launch_bounds__(256) void k_mmfold(const float* __restrict__ A,
    const float* __restrict__ dinv, const float* __restrict__ dflg,
    const float* __restrict__ B, float* __restrict__ C) {
  __shared__ float As[16][68];
  __shared__ float Bs[16][68];
  const int tid = threadIdx.x;
  const int tx = tid & 15, ty = tid >> 4;
  const int bm = blockIdx.y << 6, bn = blockIdx.x << 6;
  const int kbase = blockIdx.z << 8;
  const int lm = tid >> 2;         // 0..63
  const int lk = (tid & 3) << 2;   // 0,4,8,12
  const int lbk = tid >> 6;        // 0..3
  const int lbn = tid & 63;        // 0..63
  const int ai = bm + lm;
  const float di = dinv[ai];
  const float fl = dflg[ai];
  float acc[4][4] = {{0.f}};
  auto loadA = [&](int kg) -> float4 {
    float4 v = *(const float4*)&A[(size_t)ai * N + kg];
    const float4 dk = *(const float4*)&dinv[kg];
    int d = ai - kg;
    if ((unsigned)d < 4u) ((float*)&v)[d] += fl;
    v.x *= di * dk.x; v.y *= di * dk.y; v.z *= di * dk.z; v.w *= di * dk.w;
    return v;
  };
  float4 av = loadA(kbase + lk);
  float bv[4];
  #pragma unroll
  for (int r = 0; r < 4; ++r) bv[r] = B[(size_t)(kbase + lbk + 4 * r) * N + bn + lbn];
  for (int k0 = 0; k0 < 256; k0 += 16) {
    __syncthreads();
    As[lk + 0][lm] = av.x; As[lk + 1][lm] = av.y; As[lk + 2][lm] = av.z; As[lk + 3][lm] = av.w;
    #pragma unroll
    for (int r = 0; r < 4; ++r) Bs[lbk + 4 * r][lbn] = bv[r];
    __syncthreads();
    if (k0 + 16 < 256) {
      av = loadA(kbase + k0 + 16 + lk);
      #pragma unroll
      for (int r = 0; r < 4; ++r) bv[r] = B[(size_t)(kbase + k0 + 16 + lbk + 4 * r) * N + bn + lbn];
    }
    #pragma unroll
    for (int kk = 0; kk < 16; ++kk) {
      float4 a = *(const float4*)&As[kk][ty << 2];
      float4 b = *(const float4*)&Bs[kk][tx << 2];
      acc[0][0] = fmaf(a.x, b.x, acc[0][0]); acc[0][1] = fmaf(a.x, b.y, acc[0][1]);
      acc[0][2] = fmaf(a.x, b.z, acc[0][2]); acc[0][3] = fmaf(a.x, b.w, acc[0][3]);
      acc[1][0] = fmaf(a.y, b.x, acc[1][0]); acc[1][1] = fmaf(a.y, b.y, acc[1][1]);
      acc[1][2] = fmaf(a.y, b.z, acc[1][2]); acc[1][3] = fmaf(a.y, b.w, acc[1][3]);
      acc[2][0] = fmaf(a.z, b.x, acc[2][0]); acc[2][1] = fmaf(a.z, b.y, acc[2][1]);
      acc[2][2] = fmaf(a.z, b.z, acc[2][2]); acc[2][3] = fmaf(a.z, b.w, acc[2][3]);
      acc[3][0] = fmaf(a.w, b.x, acc[3][0]); acc[3][1] = fmaf(a.w, b.y, acc[3][1]);
      acc[3][2] = fmaf(a.w, b.z, acc[3][2]); acc[3][3] = fmaf(a.w, b.w, acc[3][3]);
    }
  }
  #pragma unroll
  for (int i = 0; i < 4; ++i)
    #pragma unroll
    for (int j = 0; j < 4; ++j)
      atomicAdd(&C[(size_t)(bm + (ty << 2) + i) * N + bn + (tx << 2) + j], acc[i][j]);
}

// ---------------- fused max(scale0(M0), scale1(M1)) + deg of result ----------------
__global__ __launch_bounds__(256) void k_maxdeg(const float* __restrict__ M0,
    const float* __restrict__ d0, const float* __restrict__ f0,
    const float* __restrict__ M1, const float* __restrict__ d1, const float* __restrict__ f1,
    float* __restrict__ Aout, float* __restrict__ dinv2, float* __restrict__ dflg2) {
  const int row = blockIdx.x;
  const int j4 = threadIdx.x;
  const float r0 = d0[row], r1 = d1[row];
  const float fl0 = f0[row], fl1 = f1[row];
  float4 a = ((const float4*)(M0 + (size_t)row * N))[j4];
  float4 b = ((const float4*)(M1 + (size_t)row * N))[j4];
  const float4 c0 = ((const float4*)d0)[j4];
  const float4 c1 = ((const float4*)d1)[j4];
  int d = row - 4 * j4;
  if ((unsigned)d < 4u) { ((float*)&a)[d] += fl0; ((float*)&b)[d] += fl1; }
  float4 o;
  o.x = fmaxf(a.x * r0 * c0.x, b.x * r1 * c1.x);
  o.y = fmaxf(a.y * r0 * c0.y, b.y * r1 * c1.y);
  o.z = fmaxf(a.z * r0 * c0.z, b.z * r1 * c1.z);
  o.w = fmaxf(a.w * r0 * c0.w, b.w * r1 * c1.w);
  ((float4*)(Aout + (size_t)row * N))[j4] = o;
  __shared__ float sdiag;
  if ((unsigned)d < 4u) sdiag = ((float*)&o)[d];
  float s = o.x + o.y + o.z + o.w;
  #pragma unroll
  for (int off = 32; off > 0; off >>= 1) s += __shfl_down(s, off, 64);
  __shared__ float red[4];
  if ((threadIdx.x & 63) == 0) red[threadIdx.x >> 6] = s;
  __syncthreads();
  if (threadIdx.x == 0) {
    float tot = red[0] + red[1] + red[2] + red[3];
    float fl = (sdiag == 0.0f) ? 1.0f : 0.0f;
    float deg = tot + fl;
    dinv2[row] = (deg > 0.0f) ? (1.0f / sqrtf(deg)) : 0.0f;
    dflg2[row] = fl;
  }
}

// ---------------- skinny matmul: out = A @ B (+bias)(+relu) ----------------
template<int K, int NCOL, bool BIAS, bool RELU>
__global__ void k_mm_small(const float* __restrict__ A, const float* __restrict__ B,
                           const float* __restrict__ bias, float* __restrict__ out) {
  const int j = threadIdx.x;
  const int i = blockIdx.x * blockDim.y + threadIdx.y;
  const float* ar = A + (size_t)i * K;
  float acc = 0.f;
  #pragma unroll 8
  for (int k = 0; k < K; ++k) acc = fmaf(ar[k], B[(size_t)k * NCOL + j], acc);
  if (BIAS) acc += bias[j];
  if (RELU) acc = fmaxf(acc, 0.f);
  out[(size_t)i * NCOL + j] = acc;
}

// ---------------- skinny matmul with fused An normalization: out = norm(BT) @ B (+bias)(+relu) ----------------
template<int NCOL, bool RELU>
__global__ void k_an_mm(const float* __restrict__ BT, const float* __restrict__ dinv,
                        const float* __restrict__ dflg, const float* __restrict__ Bm,
                        const float* __restrict__ bias, float* __restrict__ out) {
  const int j = threadIdx.x;
  const int i = blockIdx.x * blockDim.y + threadIdx.y;
  const float di = dinv[i];
  const float* ar = BT + (size_t)i * N;
  float acc = 0.f;
  #pragma unroll 8
  for (int k = 0; k < N; ++k)
    acc = fmaf(ar[k] * di * dinv[k], Bm[(size_t)k * NCOL + j], acc);
  // diagonal self-loop correction (added once)
  acc = fmaf(dflg[i] * di * dinv[i], Bm[(size_t)i * NCOL + j], acc);
  acc += bias[j];
  if (RELU) acc = fmaxf(acc, 0.f);
  out[(size_t)i * NCOL + j] = acc;
}

// ---------------- launcher ----------------
extern "C" void kernel_launch(void* const* d_in, const int* in_sizes, int n_in,
                              void* d_out, int out_size, void* d_ws, size_t ws_size,
                              hipStream_t stream) {
  const float* x     = (const float*)d_in[0];
  const float* w1    = (const float*)d_in[22];
  const float* bias1 = (const float*)d_in[23];
  const float* w2    = (const float*)d_in[24];
  const float* bias2 = (const float*)d_in[25];
  float* out = (float*)d_out;
  float* ws  = (float*)d_ws;

  float* A0 = ws + OFF_A0;
  float* A1 = ws + OFF_A1;
  float* M0 = ws + OFF_M0;
  float* M1 = ws + OFF_M1;
  float* BT = ws + OFF_BT;
  float* H1 = ws + OFF_H1;
  float* H2 = ws + OFF_H2;
  float* H3 = ws + OFF_H3;
  float* D0 = ws + OFF_D0;  float* F0 = ws + OFF_F0;
  float* D1 = ws + OFF_D1;  float* F1 = ws + OFF_F1;
  float* D2 = ws + OFF_D2;  float* F2 = ws + OFF_F2;
  float* XW1 = ws + OFF_XW1;
  float* HB  = ws + OFF_HB;
  float* HW2 = ws + OFF_HW2;

  hipMemsetAsync(A0, 0, (size_t)5 * NN * sizeof(float), stream);

  dim3 b256(256), b16(16, 16);
  k_scatter5<<<640, b256, 0, stream>>>((const int*)d_in[1], (const int*)d_in[2],
                                       (const int*)d_in[3], (const int*)d_in[4],
                                       (const int*)d_in[5], A0);

  // ---- attention block 0 (L=2) ----
  k_conv1_pool<2><<<dim3(32, 32), b16, 0, stream>>>(A0, (const float*)d_in[6], (const float*)d_in[7], H1);
  k_conv2_pool<<<dim3(17, 17), b16, 0, stream>>>(H1, (const float*)d_in[8], (const float*)d_in[9], H2);
  k_tconv1<<<dim3(17, 17), b16, 0, stream>>>(H2, (const float*)d_in[10], (const float*)d_in[11], H3);
  k_tconv2_sig<2><<<dim3(32, 32), b16, 0, stream>>>(H3, (const float*)d_in[12], (const float*)d_in[13], A0);

  // ---- attention block 1 (L=3) ----
  k_conv1_pool<3><<<dim3(32, 32), b16, 0, stream>>>(A1, (const float*)d_in[14], (const float*)d_in[15], H1);
  k_conv2_pool<<<dim3(17, 17), b16, 0, stream>>>(H1, (const float*)d_in[16], (const float*)d_in[17], H2);
  k_tconv1<<<dim3(17, 17), b16, 0, stream>>>(H2, (const float*)d_in[18], (const float*)d_in[19], H3);
  k_tconv2_sig<3><<<dim3(32, 32), b16, 0, stream>>>(H3, (const float*)d_in[20], (const float*)d_in[21], A1);

  // ---- path 0: M0prod = norm(att0_0) @ att0_1 ----
  k_deg<<<1024, b256, 0, stream>>>(A0, D0, F0);
  hipMemsetAsync(M0, 0, (size_t)NN * sizeof(float), stream);
  k_mmfold<<<dim3(16, 16, 4), b256, 0, stream>>>(A0, D0, F0, A0 + NN, M0);
  k_deg<<<1024, b256, 0, stream>>>(M0, D0, F0);

  // ---- path 1: M1prod = norm(norm(att1_0) @ att1_1) @ att1_2 ----
  k_deg<<<1024, b256, 0, stream>>>(A1, D1, F1);
  hipMemsetAsync(BT, 0, (size_t)NN * sizeof(float), stream);
  k_mmfold<<<dim3(16, 16, 4), b256, 0, stream>>>(A1, D1, F1, A1 + NN, BT);
  k_deg<<<1024, b256, 0, stream>>>(BT, D1, F1);
  hipMemsetAsync(M1, 0, (size_t)NN * sizeof(float), stream);
  k_mmfold<<<dim3(16, 16, 4), b256, 0, stream>>>(BT, D1, F1, A1 + 2 * NN, M1);
  k_deg<<<1024, b256, 0, stream>>>(M1, D1, F1);

  // ---- combine: BT = max(scale(M0), scale(M1)); deg of BT ----
  k_maxdeg<<<1024, b256, 0, stream>>>(M0, D0, F0, M1, D1, F1, BT, D2, F2);

  // ---- GCN layers (An normalization fused into the two big matmuls) ----
  k_mm_small<128, 64, false, false><<<256, dim3(64, 4), 0, stream>>>(x, w1, nullptr, XW1);
  k_an_mm<64, true><<<256, dim3(64, 4), 0, stream>>>(BT, D2, F2, XW1, bias1, HB);
  k_mm_small<64, 32, false, false><<<128, dim3(32, 8), 0, stream>>>(HB, w2, nullptr, HW2);
  k_an_mm<32, false><<<128, dim3(32, 8), 0, stream>>>(BT, D2, F2, HW2, bias2, out);
}

// Round 4
// 470.616 us; speedup vs baseline: 1.3205x; 1.3205x over previous
//
#include <hip/hip_runtime.h>
#include <math.h>

#define N 1024
#define NN (N*N)
#define NE 32768

// ---------------- workspace layout (floats) ----------------
// A:      0      .. 5NN   (att0: 2 mats, att1: 3 mats; attended in place)
// P:      5NN    .. 9NN   (4 split-K partial buffers; aliases H1_0)
// H1_0:   5NN    (16x512x512, dead after conv2)
// H1_1:   9NN    (dead after conv2) -> M0=9NN, BT=10NN, M1=11NN
// H2_0:   13NN ; H2_1: 13NN+264196
// D/F, XW1, HB, HW2 after
#define OFF_A    ((size_t)0)
#define OFF_P    ((size_t)(5*NN))
#define OFF_H10  ((size_t)(5*NN))
#define OFF_H11  ((size_t)(9*NN))
#define OFF_M0   ((size_t)(9*NN))
#define OFF_BT   ((size_t)(10*NN))
#define OFF_M1   ((size_t)(11*NN))
#define OFF_H20  ((size_t)(13*NN))
#define OFF_H21  (OFF_H20 + 264196)
#define OFF_D0   (OFF_H21 + 264196)
#define OFF_F0   (OFF_D0 + 1024)
#define OFF_D1   (OFF_F0 + 1024)
#define OFF_F1   (OFF_D1 + 1024)
#define OFF_D2   (OFF_F1 + 1024)
#define OFF_F2   (OFF_D2 + 1024)
#define OFF_XW1  (OFF_F2 + 1024)
#define OFF_HB   (OFF_XW1 + 65536)
#define OFF_HW2  (OFF_HB + 65536)

// ---------------- edge scatter (all 5 edge sets, one launch) ----------------
__global__ void k_scatter5(const int* __restrict__ e0, const int* __restrict__ e1,
                           const int* __restrict__ e2, const int* __restrict__ e3,
                           const int* __restrict__ e4, float* __restrict__ A) {
  int g = blockIdx.x * 256 + threadIdx.x;
  int seg = g >> 15;
  int k = g & 32767;
  const int* e = (seg == 0) ? e0 : (seg == 1) ? e1 : (seg == 2) ? e2 : (seg == 3) ? e3 : e4;
  atomicAdd(&A[(size_t)seg * NN + (size_t)e[k] * N + e[NE + k]], 1.0f);
}

// ---------------- conv1 (pad=1) + relu + maxpool2, both blocks in one dispatch ----------------
template<int L>
__device__ __forceinline__ void conv1_body(const float* __restrict__ A,
    const float* __restrict__ W, const float* __restrict__ Bn, float* __restrict__ out) {
  __shared__ float sIn[L][34][35];
  __shared__ float sW[16 * L * 9];
  __shared__ float sB[16];
  int tid = threadIdx.y * 16 + threadIdx.x;
  for (int i = tid; i < 16 * L * 9; i += 256) sW[i] = W[i];
  if (tid < 16) sB[tid] = Bn[tid];
  const int x0 = blockIdx.x * 32 - 1;
  const int y0 = blockIdx.y * 32 - 1;
  for (int idx = tid; idx < L * 34 * 34; idx += 256) {
    int l = idx / (34 * 34);
    int rem = idx - l * 34 * 34;
    int r = rem / 34, c = rem - r * 34;
    int iy = y0 + r, ix = x0 + c;
    sIn[l][r][c] = (iy >= 0 && iy < N && ix >= 0 && ix < N) ? A[(size_t)l * NN + (size_t)iy * N + ix] : 0.f;
  }
  __syncthreads();
  const int tx = threadIdx.x, ty = threadIdx.y;
  float p[L][4][4];
  #pragma unroll
  for (int l = 0; l < L; ++l)
    #pragma unroll
    for (int r = 0; r < 4; ++r)
      #pragma unroll
      for (int c = 0; c < 4; ++c)
        p[l][r][c] = sIn[l][2 * ty + r][2 * tx + c];
  const int ox = blockIdx.x * 16 + tx;
  const int oy = blockIdx.y * 16 + ty;
  for (int oc = 0; oc < 16; ++oc) {
    float wr[L * 9];
    #pragma unroll
    for (int t = 0; t < L * 9; ++t) wr[t] = sW[oc * L * 9 + t];
    float m = -1e30f;
    #pragma unroll
    for (int dy = 0; dy < 2; ++dy)
      #pragma unroll
      for (int dx = 0; dx < 2; ++dx) {
        float s = 0.f;
        #pragma unroll
        for (int l = 0; l < L; ++l)
          #pragma unroll
          for (int ky = 0; ky < 3; ++ky)
            #pragma unroll
            for (int kx = 0; kx < 3; ++kx)
              s = fmaf(p[l][dy + ky][dx + kx], wr[l * 9 + ky * 3 + kx], s);
        m = fmaxf(m, s);
      }
    out[(size_t)oc * 512 * 512 + (size_t)oy * 512 + ox] = fmaxf(m + sB[oc], 0.f);
  }
}

__global__ __launch_bounds__(256) void k_conv1_both(const float* __restrict__ Ab,
    const float* __restrict__ W0, const float* __restrict__ b0,
    const float* __restrict__ W1, const float* __restrict__ b1, float* __restrict__ H1b) {
  if (blockIdx.z == 0) conv1_body<2>(Ab, W0, b0, H1b);
  else                 conv1_body<3>(Ab + 2 * NN, W1, b1, H1b + 4 * NN);
}

// ---------------- conv2 (pad=2) + relu + maxpool2, both blocks, 4-ic staging ----------------
__global__ __launch_bounds__(256) void k_conv2_both(const float* __restrict__ H1b,
    const float* __restrict__ W0, const float* __restrict__ b0,
    const float* __restrict__ W1, const float* __restrict__ b1,
    float* __restrict__ H2_0, float* __restrict__ H2_1) {
  const int z = blockIdx.z;
  const float* in = H1b + (size_t)z * 4 * NN;
  const float* W  = z ? W1 : W0;
  const float* Bn = z ? b1 : b0;
  float* out = z ? H2_1 : H2_0;
  __shared__ float sIn[4][36][37];
  __shared__ float sW[4 * 16 * 9];
  __shared__ float sB[4];
  int tid = threadIdx.y * 16 + threadIdx.x;
  for (int i = tid; i < 4 * 16 * 9; i += 256) sW[i] = W[i];
  if (tid < 4) sB[tid] = Bn[tid];
  const int x0 = blockIdx.x * 32 - 2;
  const int y0 = blockIdx.y * 32 - 2;
  const int tx = threadIdx.x, ty = threadIdx.y;
  float acc[4][2][2];
  #pragma unroll
  for (int oc = 0; oc < 4; ++oc)
    #pragma unroll
    for (int dy = 0; dy < 2; ++dy)
      #pragma unroll
      for (int dx = 0; dx < 2; ++dx) acc[oc][dy][dx] = 0.f;
  for (int g = 0; g < 4; ++g) {
    __syncthreads();
    for (int idx = tid; idx < 4 * 36 * 36; idx += 256) {
      int icl = idx / 1296;
      int rem = idx - icl * 1296;
      int r = rem / 36, c = rem - r * 36;
      int iy = y0 + r, ix = x0 + c;
      sIn[icl][r][c] = (iy >= 0 && iy < 512 && ix >= 0 && ix < 512)
                       ? in[(size_t)(4 * g + icl) * 262144 + (size_t)iy * 512 + ix] : 0.f;
    }
    __syncthreads();
    #pragma unroll
    for (int icl = 0; icl < 4; ++icl) {
      float p[4][4];
      #pragma unroll
      for (int r = 0; r < 4; ++r)
        #pragma unroll
        for (int c = 0; c < 4; ++c) p[r][c] = sIn[icl][2 * ty + r][2 * tx + c];
      #pragma unroll
      for (int oc = 0; oc < 4; ++oc)
        #pragma unroll
        for (int ky = 0; ky < 3; ++ky)
          #pragma unroll
          for (int kx = 0; kx < 3; ++kx) {
            float w = sW[oc * 144 + (4 * g + icl) * 9 + ky * 3 + kx];
            #pragma unroll
            for (int dy = 0; dy < 2; ++dy)
              #pragma unroll
              for (int dx = 0; dx < 2; ++dx)
                acc[oc][dy][dx] = fmaf(p[dy + ky][dx + kx], w, acc[oc][dy][dx]);
          }
    }
  }
  const int ox = blockIdx.x * 16 + tx;
  const int oy = blockIdx.y * 16 + ty;
  if (ox < 257 && oy < 257) {
    #pragma unroll
    for (int oc = 0; oc < 4; ++oc) {
      float m = fmaxf(fmaxf(acc[oc][0][0], acc[oc][0][1]), fmaxf(acc[oc][1][0], acc[oc][1][1]));
      out[(size_t)oc * 66049 + (size_t)oy * 257 + ox] = fmaxf(m + sB[oc], 0.f);
    }
  }
}

// ---------------- fused tconv1+relu + tconv2+sigmoid + attended (A *= att), both blocks ----------------
__global__ __launch_bounds__(256) void k_tc_both(
    const float* __restrict__ H2_0, const float* __restrict__ H2_1,
    const float* __restrict__ t1w0, const float* __restrict__ t1b0,
    const float* __restrict__ t2w0, const float* __restrict__ t2b0,
    const float* __restrict__ t1w1, const float* __restrict__ t1b1,
    const float* __restrict__ t2w1, const float* __restrict__ t2b1,
    float* __restrict__ Ab) {
  const int z = blockIdx.z;
  const int L = 2 + z;
  const float* in  = z ? H2_1 : H2_0;
  const float* W1p = z ? t1w1 : t1w0;
  const float* B1p = z ? t1b1 : t1b0;
  const float* W2p = z ? t2w1 : t2w0;
  const float* B2p = z ? t2b1 : t2b0;
  float* A = Ab + (size_t)z * 2 * NN;
  __shared__ float sW1[256], sB1[16], sW2[192], sB2[3];
  int tid = threadIdx.y * 16 + threadIdx.x;
  sW1[tid] = W1p[tid];
  if (tid < 16) sB1[tid] = B1p[tid];
  for (int i = tid; i < L * 64; i += 256) sW2[i] = W2p[i];
  if (tid < L) sB2[tid] = B2p[tid];
  __syncthreads();
  const int n = blockIdx.x * 16 + threadIdx.x;   // 0..511
  const int m = blockIdx.y * 16 + threadIdx.y;   // 0..511
  const int p = m >> 1, q = n >> 1;
  const int f1y = 1 - (m & 1), f1x = 1 - (n & 1);  // flipped tconv1 kernel index
  float vin[4];
  #pragma unroll
  for (int ci = 0; ci < 4; ++ci) vin[ci] = in[(size_t)ci * 66049 + (size_t)p * 257 + q];
  float v[16];
  #pragma unroll
  for (int c = 0; c < 16; ++c) {
    float s = sB1[c];
    #pragma unroll
    for (int ci = 0; ci < 4; ++ci)
      s = fmaf(vin[ci], sW1[c * 16 + ci * 4 + f1y * 2 + f1x], s);
    v[c] = fmaxf(s, 0.f);
  }
  for (int l = 0; l < L; ++l) {
    #pragma unroll
    for (int dy = 0; dy < 2; ++dy)
      #pragma unroll
      for (int dx = 0; dx < 2; ++dx) {
        float s = sB2[l];
        #pragma unroll
        for (int c = 0; c < 16; ++c)
          s = fmaf(v[c], sW2[l * 64 + c * 4 + (1 - dy) * 2 + (1 - dx)], s);
        float sg = 1.f / (1.f + expf(-s));
        size_t idx = (size_t)l * NN + (size_t)(2 * m + dy) * N + (2 * n + dx);
        A[idx] *= sg;
      }
  }
}

// ---------------- deg of attended first hops (batched: y=0 -> A0, y=1 -> A1) ----------------
__global__ __launch_bounds__(256) void k_deg2(const float* __restrict__ Ab,
    float* __restrict__ D0, float* __restrict__ F0,
    float* __restrict__ D1, float* __restrict__ F1) {
  const int row = blockIdx.x;
  const int y = blockIdx.y;
  const float* M = Ab + (size_t)y * 2 * NN;
  float* dinv = y ? D1 : D0;
  float* dflg = y ? F1 : F0;
  const float4* r4 = (const float4*)(M + (size_t)row * N);
  float4 v = r4[threadIdx.x];
  float s = v.x + v.y + v.z + v.w;
  #pragma unroll
  for (int o = 32; o > 0; o >>= 1) s += __shfl_down(s, o, 64);
  __shared__ float red[4];
  if ((threadIdx.x & 63) == 0) red[threadIdx.x >> 6] = s;
  __syncthreads();
  if (threadIdx.x == 0) {
    float tot = red[0] + red[1] + red[2] + red[3];
    float d = M[(size_t)row * N + row];
    float fl = (d == 0.0f) ? 1.0f : 0.0f;
    float deg = tot + fl;
    dinv[row] = (deg > 0.0f) ? (1.0f / sqrtf(deg)) : 0.0f;
    dflg[row] = fl;
  }
}

// ---------------- matmul body: P = [D^-1/2 (A+fl*I) D^-1/2]@B over K slice, plain store ----------------
__device__ __forceinline__ void mm_body(const float* __restrict__ A,
    const float* __restrict__ dinv, const float* __restrict__ dflg,
    const float* __restrict__ B, float* __restrict__ C, int kbase, int klen) {
  __shared__ float As[16][68];
  __shared__ float Bs[16][68];
  const int tid = threadIdx.x;
  const int tx = tid & 15, ty = tid >> 4;
  const int bm = blockIdx.y << 6, bn = blockIdx.x << 6;
  const int lm = tid >> 2;
  const int lk = (tid & 3) << 2;
  const int lbk = tid >> 6;
  const int lbn = tid & 63;
  const int ai = bm + lm;
  const float di = dinv[ai];
  const float fl = dflg[ai];
  float acc[4][4] = {{0.f}};
  auto loadA = [&](int kg) -> float4 {
    float4 v = *(const float4*)&A[(size_t)ai * N + kg];
    const float4 dk = *(const float4*)&dinv[kg];
    int d = ai - kg;
    if ((unsigned)d < 4u) ((float*)&v)[d] += fl;
    v.x *= di * dk.x; v.y *= di * dk.y; v.z *= di * dk.z; v.w *= di * dk.w;
    return v;
  };
  float4 av = loadA(kbase + lk);
  float bv[4];
  #pragma unroll
  for (int r = 0; r < 4; ++r) bv[r] = B[(size_t)(kbase + lbk + 4 * r) * N + bn + lbn];
  for (int k0 = 0; k0 < klen; k0 += 16) {
    __syncthreads();
    As[lk + 0][lm] = av.x; As[lk + 1][lm] = av.y; As[lk + 2][lm] = av.z; As[lk + 3][lm] = av.w;
    #pragma unroll
    for (int r = 0; r < 4; ++r) Bs[lbk + 4 * r][lbn] = bv[r];
    __syncthreads();
    if (k0 + 16 < klen) {
      av = loadA(kbase + k0 + 16 + lk);
      #pragma unroll
      for (int r = 0; r < 4; ++r) bv[r] = B[(size_t)(kbase + k0 + 16 + lbk + 4 * r) * N + bn + lbn];
    }
    #pragma unroll
    for (int kk = 0; kk < 16; ++kk) {
      float4 a = *(const float4*)&As[kk][ty << 2];
      float4 b = *(const float4*)&Bs[kk][tx << 2];
      acc[0][0] = fmaf(a.x, b.x, acc[0][0]); acc[0][1] = fmaf(a.x, b.y, acc[0][1]);
      acc[0][2] = fmaf(a.x, b.z, acc[0][2]); acc[0][3] = fmaf(a.x, b.w, acc[0][3]);
      acc[1][0] = fmaf(a.y, b.x, acc[1][0]); acc[1][1] = fmaf(a.y, b.y, acc[1][1]);
      acc[1][2] = fmaf(a.y, b.z, acc[1][2]); acc[1][3] = fmaf(a.y, b.w, acc[1][3]);
      acc[2][0] = fmaf(a.z, b.x, acc[2][0]); acc[2][1] = fmaf(a.z, b.y, acc[2][1]);
      acc[2][2] = fmaf(a.z, b.z, acc[2][2]); acc[2][3] = fmaf(a.z, b.w, acc[2][3]);
      acc[3][0] = fmaf(a.w, b.x, acc[3][0]); acc[3][1] = fmaf(a.w, b.y, acc[3][1]);
      acc[3][2] = fmaf(a.w, b.z, acc[3][2]); acc[3][3] = fmaf(a.w, b.w, acc[3][3]);
    }
  }
  #pragma unroll
  for (int i = 0; i < 4; ++i) {
    float4 v = make_float4(acc[i][0], acc[i][1], acc[i][2], acc[i][3]);
    *(float4*)&C[(size_t)(bm + (ty << 2) + i) * N + bn + (tx << 2)] = v;
  }
}

// z = which*2 + kz : two independent matmuls, split-K=2 (K=512 each)
__global__ __launch_bounds__(256) void k_mm2(
    const float* __restrict__ A0, const float* __restrict__ d0, const float* __restrict__ f0, const float* __restrict__ B0,
    const float* __restrict__ A1, const float* __restrict__ d1, const float* __restrict__ f1, const float* __restrict__ B1,
    float* __restrict__ P) {
  const int z = blockIdx.z;
  const int which = z >> 1, kz = z & 1;
  if (which == 0) mm_body(A0, d0, f0, B0, P + (size_t)z * NN, kz * 512, 512);
  else            mm_body(A1, d1, f1, B1, P + (size_t)z * NN, kz * 512, 512);
}

// single matmul, split-K=4 (K=256 each)
__global__ __launch_bounds__(256) void k_mm4(
    const float* __restrict__ A, const float* __restrict__ d, const float* __restrict__ f,
    const float* __restrict__ B, float* __restrict__ P) {
  const int z = blockIdx.z;
  mm_body(A, d, f, B, P + (size_t)z * NN, z * 256, 256);
}

// ---------------- sum 2 partials + deg (batched over 2 matrices) ----------------
__global__ __launch_bounds__(256) void k_sumdeg2(const float* __restrict__ P,
    float* __restrict__ M0, float* __restrict__ BT,
    float* __restrict__ D0, float* __restrict__ F0,
    float* __restrict__ D1, float* __restrict__ F1) {
  const int row = blockIdx.x;
  const int y = blockIdx.y;
  const float4* p0 = (const float4*)(P + (size_t)(y ? 2 : 0) * NN + (size_t)row * N);
  const float4* p1 = (const float4*)(P + (size_t)(y ? 3 : 1) * NN + (size_t)row * N);
  float* dst  = y ? BT : M0;
  float* dinv = y ? D1 : D0;
  float* dflg = y ? F1 : F0;
  const int j = threadIdx.x;
  float4 a = p0[j], b = p1[j];
  float4 o = make_float4(a.x + b.x, a.y + b.y, a.z + b.z, a.w + b.w);
  ((float4*)(dst + (size_t)row * N))[j] = o;
  __shared__ float sdiag;
  int d = row - 4 * j;
  if ((unsigned)d < 4u) sdiag = ((float*)&o)[d];
  float s = o.x + o.y + o.z + o.w;
  #pragma unroll
  for (int off = 32; off > 0; off >>= 1) s += __shfl_down(s, off, 64);
  __shared__ float red[4];
  if ((j & 63) == 0) red[j >> 6] = s;
  __syncthreads();
  if (j == 0) {
    float tot = red[0] + red[1] + red[2] + red[3];
    float fl = (sdiag == 0.0f) ? 1.0f : 0.0f;
    float deg = tot + fl;
    dinv[row] = (deg > 0.0f) ? (1.0f / sqrtf(deg)) : 0.0f;
    dflg[row] = fl;
  }
}

// ---------------- sum 4 partials + deg ----------------
__global__ __launch_bounds__(256) void k_sumdeg4(const float* __restrict__ P,
    float* __restrict__ M1, float* __restrict__ D1, float* __restrict__ F1) {
  const int row = blockIdx.x;
  const int j = threadIdx.x;
  float4 o = make_float4(0.f, 0.f, 0.f, 0.f);
  #pragma unroll
  for (int t = 0; t < 4; ++t) {
    float4 a = ((const float4*)(P + (size_t)t * NN + (size_t)row * N))[j];
    o.x += a.x; o.y += a.y; o.z += a.z; o.w += a.w;
  }
  ((float4*)(M1 + (size_t)row * N))[j] = o;
  __shared__ float sdiag;
  int d = row - 4 * j;
  if ((unsigned)d < 4u) sdiag = ((float*)&o)[d];
  float s = o.x + o.y + o.z + o.w;
  #pragma unroll
  for (int off = 32; off > 0; off >>= 1) s += __shfl_down(s, off, 64);
  __shared__ float red[4];
  if ((j & 63) == 0) red[j >> 6] = s;
  __syncthreads();
  if (j == 0) {
    float tot = red[0] + red[1] + red[2] + red[3];
    float fl = (sdiag == 0.0f) ? 1.0f : 0.0f;
    float deg = tot + fl;
    D1[row] = (deg > 0.0f) ? (1.0f / sqrtf(deg)) : 0.0f;
    F1[row] = fl;
  }
}

// ---------------- fused max(scale0(M0), scale1(M1)) + deg of result ----------------
__global__ __launch_bounds__(256) void k_maxdeg(const float* __restrict__ M0,
    const float* __restrict__ d0, const float* __restrict__ f0,
    const float* __restrict__ M1, const float* __restrict__ d1, const float* __restrict__ f1,
    float* __restrict__ Aout, float* __restrict__ dinv2, float* __restrict__ dflg2) {
  const int row = blockIdx.x;
  const int j4 = threadIdx.x;
  const float r0 = d0[row], r1 = d1[row];
  const float fl0 = f0[row], fl1 = f1[row];
  float4 a = ((const float4*)(M0 + (size_t)row * N))[j4];
  float4 b = ((const float4*)(M1 + (size_t)row * N))[j4];
  const float4 c0 = ((const float4*)d0)[j4];
  const float4 c1 = ((const float4*)d1)[j4];
  int d = row - 4 * j4;
  if ((unsigned)d < 4u) { ((float*)&a)[d] += fl0; ((float*)&b)[d] += fl1; }
  float4 o;
  o.x = fmaxf(a.x * r0 * c0.x, b.x * r1 * c1.x);
  o.y = fmaxf(a.y * r0 * c0.y, b.y * r1 * c1.y);
  o.z = fmaxf(a.z * r0 * c0.z, b.z * r1 * c1.z);
  o.w = fmaxf(a.w * r0 * c0.w, b.w * r1 * c1.w);
  ((float4*)(Aout + (size_t)row * N))[j4] = o;
  __shared__ float sdiag;
  if ((unsigned)d < 4u) sdiag = ((float*)&o)[d];
  float s = o.x + o.y + o.z + o.w;
  #pragma unroll
  for (int off = 32; off > 0; off >>= 1) s += __shfl_down(s, off, 64);
  __shared__ float red[4];
  if ((threadIdx.x & 63) == 0) red[threadIdx.x >> 6] = s;
  __syncthreads();
  if (threadIdx.x == 0) {
    float tot = red[0] + red[1] + red[2] + red[3];
    float fl = (sdiag == 0.0f) ? 1.0f : 0.0f;
    float deg = tot + fl;
    dinv2[row] = (deg > 0.0f) ? (1.0f / sqrtf(deg)) : 0.0f;
    dflg2[row] = fl;
  }
}

// ---------------- skinny matmul: out = A @ B (+bias)(+relu) ----------------
template<int K, int NCOL, bool BIAS, bool RELU>
__global__ void k_mm_small(const float* __restrict__ A, const float* __restrict__ B,
                           const float* __restrict__ bias, float* __restrict__ out) {
  const int j = threadIdx.x;
  const int i = blockIdx.x * blockDim.y + threadIdx.y;
  const float* ar = A + (size_t)i * K;
  float acc = 0.f;
  #pragma unroll 8
  for (int k = 0; k < K; ++k) acc = fmaf(ar[k], B[(size_t)k * NCOL + j], acc);
  if (BIAS) acc += bias[j];
  if (RELU) acc = fmaxf(acc, 0.f);
  out[(size_t)i * NCOL + j] = acc;
}

// ---------------- skinny matmul with fused An normalization ----------------
template<int NCOL, bool RELU>
__global__ void k_an_mm(const float* __restrict__ BT, const float* __restrict__ dinv,
                        const float* __restrict__ dflg, const float* __restrict__ Bm,
                        const float* __restrict__ bias, float* __restrict__ out) {
  const int j = threadIdx.x;
  const int i = blockIdx.x * blockDim.y + threadIdx.y;
  const float di = dinv[i];
  const float* ar = BT + (size_t)i * N;
  float acc = 0.f;
  #pragma unroll 8
  for (int k = 0; k < N; ++k)
    acc = fmaf(ar[k] * di * dinv[k], Bm[(size_t)k * NCOL + j], acc);
  acc = fmaf(dflg[i] * di * dinv[i], Bm[(size_t)i * NCOL + j], acc);
  acc += bias[j];
  if (RELU) acc = fmaxf(acc, 0.f);
  out[(size_t)i * NCOL + j] = acc;
}

// ---------------- launcher ----------------
extern "C" void kernel_launch(void* const* d_in, const int* in_sizes, int n_in,
                              void* d_out, int out_size, void* d_ws, size_t ws_size,
                              hipStream_t stream) {
  const float* x     = (const float*)d_in[0];
  const float* w1    = (const float*)d_in[22];
  const float* bias1 = (const float*)d_in[23];
  const float* w2    = (const float*)d_in[24];
  const float* bias2 = (const float*)d_in[25];
  float* out = (float*)d_out;
  float* ws  = (float*)d_ws;

  float* A  = ws + OFF_A;
  float* P  = ws + OFF_P;
  float* H1 = ws + OFF_H10;
  float* M0 = ws + OFF_M0;
  float* BT = ws + OFF_BT;
  float* M1 = ws + OFF_M1;
  float* H2_0 = ws + OFF_H20;
  float* H2_1 = ws + OFF_H21;
  float* D0 = ws + OFF_D0;  float* F0 = ws + OFF_F0;
  float* D1 = ws + OFF_D1;  float* F1 = ws + OFF_F1;
  float* D2 = ws + OFF_D2;  float* F2 = ws + OFF_F2;
  float* XW1 = ws + OFF_XW1;
  float* HB  = ws + OFF_HB;
  float* HW2 = ws + OFF_HW2;

  hipMemsetAsync(A, 0, (size_t)5 * NN * sizeof(float), stream);

  dim3 b256(256), b16(16, 16);
  // independent: x @ w1
  k_mm_small<128, 64, false, false><<<256, dim3(64, 4), 0, stream>>>(x, w1, nullptr, XW1);

  k_scatter5<<<640, b256, 0, stream>>>((const int*)d_in[1], (const int*)d_in[2],
                                       (const int*)d_in[3], (const int*)d_in[4],
                                       (const int*)d_in[5], A);

  // attention encoders, both blocks batched per stage
  k_conv1_both<<<dim3(32, 32, 2), b16, 0, stream>>>(A,
      (const float*)d_in[6], (const float*)d_in[7],
      (const float*)d_in[14], (const float*)d_in[15], H1);
  k_conv2_both<<<dim3(17, 17, 2), b16, 0, stream>>>(H1,
      (const float*)d_in[8], (const float*)d_in[9],
      (const float*)d_in[16], (const float*)d_in[17], H2_0, H2_1);
  k_tc_both<<<dim3(32, 32, 2), b16, 0, stream>>>(H2_0, H2_1,
      (const float*)d_in[10], (const float*)d_in[11],
      (const float*)d_in[12], (const float*)d_in[13],
      (const float*)d_in[18], (const float*)d_in[19],
      (const float*)d_in[20], (const float*)d_in[21], A);

  // first-hop degrees for both paths (batched)
  k_deg2<<<dim3(1024, 2), b256, 0, stream>>>(A, D0, F0, D1, F1);

  // hop-1 matmuls for both paths, batched, split-K=2, plain-store partials
  k_mm2<<<dim3(16, 16, 4), b256, 0, stream>>>(A, D0, F0, A + NN,
                                              A + 2 * NN, D1, F1, A + 3 * NN, P);
  k_sumdeg2<<<dim3(1024, 2), b256, 0, stream>>>(P, M0, BT, D0, F0, D1, F1);

  // path1 hop-2 matmul, split-K=4
  k_mm4<<<dim3(16, 16, 4), b256, 0, stream>>>(BT, D1, F1, A + 4 * NN, P);
  k_sumdeg4<<<1024, b256, 0, stream>>>(P, M1, D1, F1);

  // combine + final deg
  k_maxdeg<<<1024, b256, 0, stream>>>(M0, D0, F0, M1, D1, F1, BT, D2, F2);

  // GCN layers (An normalization fused)
  k_an_mm<64, true><<<256, dim3(64, 4), 0, stream>>>(BT, D2, F2, XW1, bias1, HB);
  k_mm_small<64, 32, false, false><<<128, dim3(32, 8), 0, stream>>>(HB, w2, nullptr, HW2);
  k_an_mm<32, false><<<128, dim3(32, 8), 0, stream>>>(BT, D2, F2, HW2, bias2, out);
}

// Round 5
// 432.029 us; speedup vs baseline: 1.4385x; 1.0893x over previous
//
#include <hip/hip_runtime.h>
#include <math.h>

#define N 1024
#define NN (N*N)
#define NE 32768

// ---------------- workspace layout (floats) ----------------
// A:   0..5NN    (att0: 2 mats, att1: 3 mats; attended in place)
// H1:  5..13NN   (conv1 out, dead after conv2) -> reused as 8 mm2 split-K partials
//   after sumdeg2: M0 = 5NN (in-place), BT = 9NN (in-place); 6,7,8,10,11,12 dead
// mm4 partials: Pa = 10NN (z<3), Pb = 6NN (z==3); M1 = 10NN in-place; AN = 11NN
// H2_0 = 13NN, H2_1 = 13NN+264196; D/F, XW1, HB, HW2 after
#define OFF_A    ((size_t)0)
#define OFF_P    ((size_t)(5*NN))
#define OFF_H10  ((size_t)(5*NN))
#define OFF_H20  ((size_t)(13*NN))
#define OFF_H21  (OFF_H20 + 264196)
#define OFF_D0   (OFF_H21 + 264196)
#define OFF_F0   (OFF_D0 + 1024)
#define OFF_D1   (OFF_F0 + 1024)
#define OFF_F1   (OFF_D1 + 1024)
#define OFF_D2   (OFF_F1 + 1024)
#define OFF_F2   (OFF_D2 + 1024)
#define OFF_XW1  (OFF_F2 + 1024)
#define OFF_HB   (OFF_XW1 + 65536)
#define OFF_HW2  (OFF_HB + 65536)

// ---------------- edge scatter (all 5 edge sets, one launch) ----------------
__global__ void k_scatter5(const int* __restrict__ e0, const int* __restrict__ e1,
                           const int* __restrict__ e2, const int* __restrict__ e3,
                           const int* __restrict__ e4, float* __restrict__ A) {
  int g = blockIdx.x * 256 + threadIdx.x;
  int seg = g >> 15;
  int k = g & 32767;
  const int* e = (seg == 0) ? e0 : (seg == 1) ? e1 : (seg == 2) ? e2 : (seg == 3) ? e3 : e4;
  atomicAdd(&A[(size_t)seg * NN + (size_t)e[k] * N + e[NE + k]], 1.0f);
}

// ---------------- conv1 (pad=1) + relu + maxpool2, both blocks in one dispatch ----------------
template<int L>
__device__ __forceinline__ void conv1_body(const float* __restrict__ A,
    const float* __restrict__ W, const float* __restrict__ Bn, float* __restrict__ out) {
  __shared__ float sIn[L][34][35];
  __shared__ float sW[16 * L * 9];
  __shared__ float sB[16];
  int tid = threadIdx.y * 16 + threadIdx.x;
  for (int i = tid; i < 16 * L * 9; i += 256) sW[i] = W[i];
  if (tid < 16) sB[tid] = Bn[tid];
  const int x0 = blockIdx.x * 32 - 1;
  const int y0 = blockIdx.y * 32 - 1;
  for (int idx = tid; idx < L * 34 * 34; idx += 256) {
    int l = idx / (34 * 34);
    int rem = idx - l * 34 * 34;
    int r = rem / 34, c = rem - r * 34;
    int iy = y0 + r, ix = x0 + c;
    sIn[l][r][c] = (iy >= 0 && iy < N && ix >= 0 && ix < N) ? A[(size_t)l * NN + (size_t)iy * N + ix] : 0.f;
  }
  __syncthreads();
  const int tx = threadIdx.x, ty = threadIdx.y;
  float p[L][4][4];
  #pragma unroll
  for (int l = 0; l < L; ++l)
    #pragma unroll
    for (int r = 0; r < 4; ++r)
      #pragma unroll
      for (int c = 0; c < 4; ++c)
        p[l][r][c] = sIn[l][2 * ty + r][2 * tx + c];
  const int ox = blockIdx.x * 16 + tx;
  const int oy = blockIdx.y * 16 + ty;
  for (int oc = 0; oc < 16; ++oc) {
    float wr[L * 9];
    #pragma unroll
    for (int t = 0; t < L * 9; ++t) wr[t] = sW[oc * L * 9 + t];
    float m = -1e30f;
    #pragma unroll
    for (int dy = 0; dy < 2; ++dy)
      #pragma unroll
      for (int dx = 0; dx < 2; ++dx) {
        float s = 0.f;
        #pragma unroll
        for (int l = 0; l < L; ++l)
          #pragma unroll
          for (int ky = 0; ky < 3; ++ky)
            #pragma unroll
            for (int kx = 0; kx < 3; ++kx)
              s = fmaf(p[l][dy + ky][dx + kx], wr[l * 9 + ky * 3 + kx], s);
        m = fmaxf(m, s);
      }
    out[(size_t)oc * 512 * 512 + (size_t)oy * 512 + ox] = fmaxf(m + sB[oc], 0.f);
  }
}

__global__ __launch_bounds__(256) void k_conv1_both(const float* __restrict__ Ab,
    const float* __restrict__ W0, const float* __restrict__ b0,
    const float* __restrict__ W1, const float* __restrict__ b1, float* __restrict__ H1b) {
  if (blockIdx.z == 0) conv1_body<2>(Ab, W0, b0, H1b);
  else                 conv1_body<3>(Ab + 2 * NN, W1, b1, H1b + 4 * NN);
}

// ---------------- conv2 (pad=2) + relu + maxpool2, both blocks, 4-ic staging ----------------
__global__ __launch_bounds__(256) void k_conv2_both(const float* __restrict__ H1b,
    const float* __restrict__ W0, const float* __restrict__ b0,
    const float* __restrict__ W1, const float* __restrict__ b1,
    float* __restrict__ H2_0, float* __restrict__ H2_1) {
  const int z = blockIdx.z;
  const float* in = H1b + (size_t)z * 4 * NN;
  const float* W  = z ? W1 : W0;
  const float* Bn = z ? b1 : b0;
  float* out = z ? H2_1 : H2_0;
  __shared__ float sIn[4][36][37];
  __shared__ float sW[4 * 16 * 9];
  __shared__ float sB[4];
  int tid = threadIdx.y * 16 + threadIdx.x;
  for (int i = tid; i < 4 * 16 * 9; i += 256) sW[i] = W[i];
  if (tid < 4) sB[tid] = Bn[tid];
  const int x0 = blockIdx.x * 32 - 2;
  const int y0 = blockIdx.y * 32 - 2;
  const int tx = threadIdx.x, ty = threadIdx.y;
  float acc[4][2][2];
  #pragma unroll
  for (int oc = 0; oc < 4; ++oc)
    #pragma unroll
    for (int dy = 0; dy < 2; ++dy)
      #pragma unroll
      for (int dx = 0; dx < 2; ++dx) acc[oc][dy][dx] = 0.f;
  for (int g = 0; g < 4; ++g) {
    __syncthreads();
    for (int idx = tid; idx < 4 * 36 * 36; idx += 256) {
      int icl = idx / 1296;
      int rem = idx - icl * 1296;
      int r = rem / 36, c = rem - r * 36;
      int iy = y0 + r, ix = x0 + c;
      sIn[icl][r][c] = (iy >= 0 && iy < 512 && ix >= 0 && ix < 512)
                       ? in[(size_t)(4 * g + icl) * 262144 + (size_t)iy * 512 + ix] : 0.f;
    }
    __syncthreads();
    #pragma unroll
    for (int icl = 0; icl < 4; ++icl) {
      float p[4][4];
      #pragma unroll
      for (int r = 0; r < 4; ++r)
        #pragma unroll
        for (int c = 0; c < 4; ++c) p[r][c] = sIn[icl][2 * ty + r][2 * tx + c];
      #pragma unroll
      for (int oc = 0; oc < 4; ++oc)
        #pragma unroll
        for (int ky = 0; ky < 3; ++ky)
          #pragma unroll
          for (int kx = 0; kx < 3; ++kx) {
            float w = sW[oc * 144 + (4 * g + icl) * 9 + ky * 3 + kx];
            #pragma unroll
            for (int dy = 0; dy < 2; ++dy)
              #pragma unroll
              for (int dx = 0; dx < 2; ++dx)
                acc[oc][dy][dx] = fmaf(p[dy + ky][dx + kx], w, acc[oc][dy][dx]);
          }
    }
  }
  const int ox = blockIdx.x * 16 + tx;
  const int oy = blockIdx.y * 16 + ty;
  if (ox < 257 && oy < 257) {
    #pragma unroll
    for (int oc = 0; oc < 4; ++oc) {
      float m = fmaxf(fmaxf(acc[oc][0][0], acc[oc][0][1]), fmaxf(acc[oc][1][0], acc[oc][1][1]));
      out[(size_t)oc * 66049 + (size_t)oy * 257 + ox] = fmaxf(m + sB[oc], 0.f);
    }
  }
}

// ---------------- fused tconv1+relu + tconv2+sigmoid + attended (A *= att), both blocks ----------------
__global__ __launch_bounds__(256) void k_tc_both(
    const float* __restrict__ H2_0, const float* __restrict__ H2_1,
    const float* __restrict__ t1w0, const float* __restrict__ t1b0,
    const float* __restrict__ t2w0, const float* __restrict__ t2b0,
    const float* __restrict__ t1w1, const float* __restrict__ t1b1,
    const float* __restrict__ t2w1, const float* __restrict__ t2b1,
    float* __restrict__ Ab) {
  const int z = blockIdx.z;
  const int L = 2 + z;
  const float* in  = z ? H2_1 : H2_0;
  const float* W1p = z ? t1w1 : t1w0;
  const float* B1p = z ? t1b1 : t1b0;
  const float* W2p = z ? t2w1 : t2w0;
  const float* B2p = z ? t2b1 : t2b0;
  float* A = Ab + (size_t)z * 2 * NN;
  __shared__ float sW1[256], sB1[16], sW2[192], sB2[3];
  int tid = threadIdx.y * 16 + threadIdx.x;
  sW1[tid] = W1p[tid];
  if (tid < 16) sB1[tid] = B1p[tid];
  for (int i = tid; i < L * 64; i += 256) sW2[i] = W2p[i];
  if (tid < L) sB2[tid] = B2p[tid];
  __syncthreads();
  const int n = blockIdx.x * 16 + threadIdx.x;   // 0..511
  const int m = blockIdx.y * 16 + threadIdx.y;   // 0..511
  const int p = m >> 1, q = n >> 1;
  const int f1y = 1 - (m & 1), f1x = 1 - (n & 1);
  float vin[4];
  #pragma unroll
  for (int ci = 0; ci < 4; ++ci) vin[ci] = in[(size_t)ci * 66049 + (size_t)p * 257 + q];
  float v[16];
  #pragma unroll
  for (int c = 0; c < 16; ++c) {
    float s = sB1[c];
    #pragma unroll
    for (int ci = 0; ci < 4; ++ci)
      s = fmaf(vin[ci], sW1[c * 16 + ci * 4 + f1y * 2 + f1x], s);
    v[c] = fmaxf(s, 0.f);
  }
  for (int l = 0; l < L; ++l) {
    #pragma unroll
    for (int dy = 0; dy < 2; ++dy)
      #pragma unroll
      for (int dx = 0; dx < 2; ++dx) {
        float s = sB2[l];
        #pragma unroll
        for (int c = 0; c < 16; ++c)
          s = fmaf(v[c], sW2[l * 64 + c * 4 + (1 - dy) * 2 + (1 - dx)], s);
        float sg = 1.f / (1.f + expf(-s));
        size_t idx = (size_t)l * NN + (size_t)(2 * m + dy) * N + (2 * n + dx);
        A[idx] *= sg;
      }
  }
}

// ---------------- deg of attended first hops (batched: y=0 -> A0, y=1 -> A1) ----------------
__global__ __launch_bounds__(256) void k_deg2(const float* __restrict__ Ab,
    float* __restrict__ D0, float* __restrict__ F0,
    float* __restrict__ D1, float* __restrict__ F1) {
  const int row = blockIdx.x;
  const int y = blockIdx.y;
  const float* M = Ab + (size_t)y * 2 * NN;
  float* dinv = y ? D1 : D0;
  float* dflg = y ? F1 : F0;
  const float4* r4 = (const float4*)(M + (size_t)row * N);
  float4 v = r4[threadIdx.x];
  float s = v.x + v.y + v.z + v.w;
  #pragma unroll
  for (int o = 32; o > 0; o >>= 1) s += __shfl_down(s, o, 64);
  __shared__ float red[4];
  if ((threadIdx.x & 63) == 0) red[threadIdx.x >> 6] = s;
  __syncthreads();
  if (threadIdx.x == 0) {
    float tot = red[0] + red[1] + red[2] + red[3];
    float d = M[(size_t)row * N + row];
    float fl = (d == 0.0f) ? 1.0f : 0.0f;
    float deg = tot + fl;
    dinv[row] = (deg > 0.0f) ? (1.0f / sqrtf(deg)) : 0.0f;
    dflg[row] = fl;
  }
}

// ---------------- 128x128 tile, 8x8/thread matmul body with fused left-normalization ----------------
// C_partial = [D^-1/2 (A + fl*I) D^-1/2] @ B over K-range [kbase, kbase+klen)
__device__ __forceinline__ void mm_body128(const float* __restrict__ A,
    const float* __restrict__ dinv, const float* __restrict__ dflg,
    const float* __restrict__ B, float* __restrict__ C, int kbase, int klen) {
  __shared__ float As[16][132];  // [k][m], +4 pad
  __shared__ float Bs[16][128];  // [k][n]
  const int tid = threadIdx.x;
  const int tx = tid & 15, ty = tid >> 4;
  const int bm = blockIdx.y << 7, bn = blockIdx.x << 7;
  const int ar = tid >> 2;            // 0..63
  const int ac = (tid & 3) << 2;      // 0,4,8,12
  const int br = tid >> 5;            // 0..7
  const int bc = (tid & 31) << 2;     // 0..124
  const int ai0 = bm + ar, ai1 = ai0 + 64;
  const float di0 = dinv[ai0], fl0 = dflg[ai0];
  const float di1 = dinv[ai1], fl1 = dflg[ai1];
  float acc[8][8];
  #pragma unroll
  for (int i = 0; i < 8; ++i)
    #pragma unroll
    for (int j = 0; j < 8; ++j) acc[i][j] = 0.f;

  auto loadA = [&](int row, float di, float fl, int kg) -> float4 {
    float4 v = *(const float4*)&A[(size_t)row * N + kg];
    const float4 dk = *(const float4*)&dinv[kg];
    int d = row - kg;
    if ((unsigned)d < 4u) ((float*)&v)[d] += fl;
    v.x *= di * dk.x; v.y *= di * dk.y; v.z *= di * dk.z; v.w *= di * dk.w;
    return v;
  };
  float4 av0 = loadA(ai0, di0, fl0, kbase + ac);
  float4 av1 = loadA(ai1, di1, fl1, kbase + ac);
  float4 bv0 = *(const float4*)&B[(size_t)(kbase + br) * N + bn + bc];
  float4 bv1 = *(const float4*)&B[(size_t)(kbase + br + 8) * N + bn + bc];
  for (int k0 = 0; k0 < klen; k0 += 16) {
    __syncthreads();
    As[ac + 0][ar] = av0.x; As[ac + 1][ar] = av0.y; As[ac + 2][ar] = av0.z; As[ac + 3][ar] = av0.w;
    As[ac + 0][ar + 64] = av1.x; As[ac + 1][ar + 64] = av1.y; As[ac + 2][ar + 64] = av1.z; As[ac + 3][ar + 64] = av1.w;
    *(float4*)&Bs[br][bc] = bv0;
    *(float4*)&Bs[br + 8][bc] = bv1;
    __syncthreads();
    if (k0 + 16 < klen) {
      int kg = kbase + k0 + 16;
      av0 = loadA(ai0, di0, fl0, kg + ac);
      av1 = loadA(ai1, di1, fl1, kg + ac);
      bv0 = *(const float4*)&B[(size_t)(kg + br) * N + bn + bc];
      bv1 = *(const float4*)&B[(size_t)(kg + br + 8) * N + bn + bc];
    }
    #pragma unroll
    for (int kk = 0; kk < 16; ++kk) {
      float4 a0 = *(const float4*)&As[kk][ty << 2];
      float4 a1 = *(const float4*)&As[kk][64 + (ty << 2)];
      float4 b0 = *(const float4*)&Bs[kk][tx << 2];
      float4 b1 = *(const float4*)&Bs[kk][64 + (tx << 2)];
      float av[8] = {a0.x, a0.y, a0.z, a0.w, a1.x, a1.y, a1.z, a1.w};
      float bv[8] = {b0.x, b0.y, b0.z, b0.w, b1.x, b1.y, b1.z, b1.w};
      #pragma unroll
      for (int i = 0; i < 8; ++i)
        #pragma unroll
        for (int j = 0; j < 8; ++j)
          acc[i][j] = fmaf(av[i], bv[j], acc[i][j]);
    }
  }
  #pragma unroll
  for (int i = 0; i < 8; ++i) {
    int row = bm + ((i < 4) ? ((ty << 2) + i) : (64 + (ty << 2) + i - 4));
    *(float4*)&C[(size_t)row * N + bn + (tx << 2)] =
        make_float4(acc[i][0], acc[i][1], acc[i][2], acc[i][3]);
    *(float4*)&C[(size_t)row * N + bn + 64 + (tx << 2)] =
        make_float4(acc[i][4], acc[i][5], acc[i][6], acc[i][7]);
  }
}

// two independent matmuls, split-K=4 each; z = which*4 + kz
__global__ __launch_bounds__(256) void k_mm2(
    const float* __restrict__ A0, const float* __restrict__ d0, const float* __restrict__ f0, const float* __restrict__ B0,
    const float* __restrict__ A1, const float* __restrict__ d1, const float* __restrict__ f1, const float* __restrict__ B1,
    float* __restrict__ P) {
  const int z = blockIdx.z;
  const int which = z >> 2, kz = z & 3;
  if (which == 0) mm_body128(A0, d0, f0, B0, P + (size_t)z * NN, kz * 256, 256);
  else            mm_body128(A1, d1, f1, B1, P + (size_t)z * NN, kz * 256, 256);
}

// single matmul, split-K=4; partials z<3 -> Pa+z*NN, z==3 -> Pb
__global__ __launch_bounds__(256) void k_mm4(
    const float* __restrict__ A, const float* __restrict__ d, const float* __restrict__ f,
    const float* __restrict__ B, float* __restrict__ Pa, float* __restrict__ Pb) {
  const int z = blockIdx.z;
  float* dst = (z < 3) ? (Pa + (size_t)z * NN) : Pb;
  mm_body128(A, d, f, B, dst, z * 256, 256);
}

// ---------------- sum 4 partials + deg, in place (dst = first partial), batched over 2 ----------------
__global__ __launch_bounds__(256) void k_sumdeg2(float* __restrict__ P,
    float* __restrict__ D0p, float* __restrict__ F0p,
    float* __restrict__ D1p, float* __restrict__ F1p) {
  const int row = blockIdx.x;
  const int y = blockIdx.y;
  float* base = P + (size_t)y * 4 * NN;
  const int j = threadIdx.x;
  float4 o = make_float4(0.f, 0.f, 0.f, 0.f);
  #pragma unroll
  for (int t = 0; t < 4; ++t) {
    float4 a = ((const float4*)(base + (size_t)t * NN + (size_t)row * N))[j];
    o.x += a.x; o.y += a.y; o.z += a.z; o.w += a.w;
  }
  ((float4*)(base + (size_t)row * N))[j] = o;
  __shared__ float sdiag;
  int d = row - 4 * j;
  if ((unsigned)d < 4u) sdiag = ((float*)&o)[d];
  float s = o.x + o.y + o.z + o.w;
  #pragma unroll
  for (int off = 32; off > 0; off >>= 1) s += __shfl_down(s, off, 64);
  __shared__ float red[4];
  if ((j & 63) == 0) red[j >> 6] = s;
  __syncthreads();
  if (j == 0) {
    float tot = red[0] + red[1] + red[2] + red[3];
    float fl = (sdiag == 0.0f) ? 1.0f : 0.0f;
    float deg = tot + fl;
    float* dinv = y ? D1p : D0p;
    float* dflg = y ? F1p : F0p;
    dinv[row] = (deg > 0.0f) ? (1.0f / sqrtf(deg)) : 0.0f;
    dflg[row] = fl;
  }
}

// ---------------- sum 4 partials (Pa x3 + Pb) + deg; dst = Pa ----------------
__global__ __launch_bounds__(256) void k_sumdeg4(float* __restrict__ Pa, const float* __restrict__ Pb,
    float* __restrict__ D1, float* __restrict__ F1) {
  const int row = blockIdx.x;
  const int j = threadIdx.x;
  float4 o = make_float4(0.f, 0.f, 0.f, 0.f);
  #pragma unroll
  for (int t = 0; t < 3; ++t) {
    float4 a = ((const float4*)(Pa + (size_t)t * NN + (size_t)row * N))[j];
    o.x += a.x; o.y += a.y; o.z += a.z; o.w += a.w;
  }
  {
    float4 a = ((const float4*)(Pb + (size_t)row * N))[j];
    o.x += a.x; o.y += a.y; o.z += a.z; o.w += a.w;
  }
  ((float4*)(Pa + (size_t)row * N))[j] = o;
  __shared__ float sdiag;
  int d = row - 4 * j;
  if ((unsigned)d < 4u) sdiag = ((float*)&o)[d];
  float s = o.x + o.y + o.z + o.w;
  #pragma unroll
  for (int off = 32; off > 0; off >>= 1) s += __shfl_down(s, off, 64);
  __shared__ float red[4];
  if ((j & 63) == 0) red[j >> 6] = s;
  __syncthreads();
  if (j == 0) {
    float tot = red[0] + red[1] + red[2] + red[3];
    float fl = (sdiag == 0.0f) ? 1.0f : 0.0f;
    float deg = tot + fl;
    D1[row] = (deg > 0.0f) ? (1.0f / sqrtf(deg)) : 0.0f;
    F1[row] = fl;
  }
}

// ---------------- fused max(scale0(M0), scale1(M1)) + deg of result ----------------
__global__ __launch_bounds__(256) void k_maxdeg(const float* __restrict__ M0,
    const float* __restrict__ d0, const float* __restrict__ f0,
    const float* __restrict__ M1, const float* __restrict__ d1, const float* __restrict__ f1,
    float* __restrict__ Aout, float* __restrict__ dinv2, float* __restrict__ dflg2) {
  const int row = blockIdx.x;
  const int j4 = threadIdx.x;
  const float r0 = d0[row], r1 = d1[row];
  const float fl0 = f0[row], fl1 = f1[row];
  float4 a = ((const float4*)(M0 + (size_t)row * N))[j4];
  float4 b = ((const float4*)(M1 + (size_t)row * N))[j4];
  const float4 c0 = ((const float4*)d0)[j4];
  const float4 c1 = ((const float4*)d1)[j4];
  int d = row - 4 * j4;
  if ((unsigned)d < 4u) { ((float*)&a)[d] += fl0; ((float*)&b)[d] += fl1; }
  float4 o;
  o.x = fmaxf(a.x * r0 * c0.x, b.x * r1 * c1.x);
  o.y = fmaxf(a.y * r0 * c0.y, b.y * r1 * c1.y);
  o.z = fmaxf(a.z * r0 * c0.z, b.z * r1 * c1.z);
  o.w = fmaxf(a.w * r0 * c0.w, b.w * r1 * c1.w);
  ((float4*)(Aout + (size_t)row * N))[j4] = o;
  __shared__ float sdiag;
  if ((unsigned)d < 4u) sdiag = ((float*)&o)[d];
  float s = o.x + o.y + o.z + o.w;
  #pragma unroll
  for (int off = 32; off > 0; off >>= 1) s += __shfl_down(s, off, 64);
  __shared__ float red[4];
  if ((threadIdx.x & 63) == 0) red[threadIdx.x >> 6] = s;
  __syncthreads();
  if (threadIdx.x == 0) {
    float tot = red[0] + red[1] + red[2] + red[3];
    float fl = (sdiag == 0.0f) ? 1.0f : 0.0f;
    float deg = tot + fl;
    dinv2[row] = (deg > 0.0f) ? (1.0f / sqrtf(deg)) : 0.0f;
    dflg2[row] = fl;
  }
}

// ---------------- skinny matmul: out = A @ B (+bias)(+relu) ----------------
template<int K, int NCOL, bool BIAS, bool RELU>
__global__ void k_mm_small(const float* __restrict__ A, const float* __restrict__ B,
                           const float* __restrict__ bias, float* __restrict__ out) {
  const int j = threadIdx.x;
  const int i = blockIdx.x * blockDim.y + threadIdx.y;
  const float* ar = A + (size_t)i * K;
  float acc = 0.f;
  #pragma unroll 8
  for (int k = 0; k < K; ++k) acc = fmaf(ar[k], B[(size_t)k * NCOL + j], acc);
  if (BIAS) acc += bias[j];
  if (RELU) acc = fmaxf(acc, 0.f);
  out[(size_t)i * NCOL + j] = acc;
}

// ---------------- skinny matmul with fused An normalization ----------------
template<int NCOL, bool RELU>
__global__ void k_an_mm(const float* __restrict__ BT, const float* __restrict__ dinv,
                        const float* __restrict__ dflg, const float* __restrict__ Bm,
                        const float* __restrict__ bias, float* __restrict__ out) {
  const int j = threadIdx.x;
  const int i = blockIdx.x * blockDim.y + threadIdx.y;
  const float di = dinv[i];
  const float* ar = BT + (size_t)i * N;
  float acc = 0.f;
  for (int k = 0; k < N; k += 4) {
    float4 a4 = *(const float4*)&ar[k];
    float4 d4 = *(const float4*)&dinv[k];
    acc = fmaf(a4.x * d4.x, Bm[(size_t)(k + 0) * NCOL + j], acc);
    acc = fmaf(a4.y * d4.y, Bm[(size_t)(k + 1) * NCOL + j], acc);
    acc = fmaf(a4.z * d4.z, Bm[(size_t)(k + 2) * NCOL + j], acc);
    acc = fmaf(a4.w * d4.w, Bm[(size_t)(k + 3) * NCOL + j], acc);
  }
  acc = fmaf(dflg[i] * dinv[i], Bm[(size_t)i * NCOL + j], acc);
  acc = fmaf(di, acc, bias[j]);
  if (RELU) acc = fmaxf(acc, 0.f);
  out[(size_t)i * NCOL + j] = acc;
}

// ---------------- launcher ----------------
extern "C" void kernel_launch(void* const* d_in, const int* in_sizes, int n_in,
                              void* d_out, int out_size, void* d_ws, size_t ws_size,
                              hipStream_t stream) {
  const float* x     = (const float*)d_in[0];
  const float* w1    = (const float*)d_in[22];
  const float* bias1 = (const float*)d_in[23];
  const float* w2    = (const float*)d_in[24];
  const float* bias2 = (const float*)d_in[25];
  float* out = (float*)d_out;
  float* ws  = (float*)d_ws;

  float* A  = ws + OFF_A;
  float* P  = ws + OFF_P;           // 8 partials: 5..13NN (aliases H1)
  float* H1 = ws + OFF_H10;
  float* H2_0 = ws + OFF_H20;
  float* H2_1 = ws + OFF_H21;
  float* M0 = ws + (size_t)5 * NN;  // = P[0] after in-place reduce
  float* BT = ws + (size_t)9 * NN;  // = P[4] after in-place reduce
  float* Pa = ws + (size_t)10 * NN; // mm4 partials z<3
  float* Pb = ws + (size_t)6 * NN;  // mm4 partial z==3
  float* M1 = ws + (size_t)10 * NN; // = Pa[0] after in-place reduce
  float* AN = ws + (size_t)11 * NN;
  float* D0 = ws + OFF_D0;  float* F0 = ws + OFF_F0;
  float* D1 = ws + OFF_D1;  float* F1 = ws + OFF_F1;
  float* D2 = ws + OFF_D2;  float* F2 = ws + OFF_F2;
  float* XW1 = ws + OFF_XW1;
  float* HB  = ws + OFF_HB;
  float* HW2 = ws + OFF_HW2;

  hipMemsetAsync(A, 0, (size_t)5 * NN * sizeof(float), stream);

  dim3 b256(256), b16(16, 16);
  // independent: x @ w1
  k_mm_small<128, 64, false, false><<<256, dim3(64, 4), 0, stream>>>(x, w1, nullptr, XW1);

  k_scatter5<<<640, b256, 0, stream>>>((const int*)d_in[1], (const int*)d_in[2],
                                       (const int*)d_in[3], (const int*)d_in[4],
                                       (const int*)d_in[5], A);

  // attention encoders, both blocks batched per stage
  k_conv1_both<<<dim3(32, 32, 2), b16, 0, stream>>>(A,
      (const float*)d_in[6], (const float*)d_in[7],
      (const float*)d_in[14], (const float*)d_in[15], H1);
  k_conv2_both<<<dim3(17, 17, 2), b16, 0, stream>>>(H1,
      (const float*)d_in[8], (const float*)d_in[9],
      (const float*)d_in[16], (const float*)d_in[17], H2_0, H2_1);
  k_tc_both<<<dim3(32, 32, 2), b16, 0, stream>>>(H2_0, H2_1,
      (const float*)d_in[10], (const float*)d_in[11],
      (const float*)d_in[12], (const float*)d_in[13],
      (const float*)d_in[18], (const float*)d_in[19],
      (const float*)d_in[20], (const float*)d_in[21], A);

  // first-hop degrees for both paths (batched)
  k_deg2<<<dim3(1024, 2), b256, 0, stream>>>(A, D0, F0, D1, F1);

  // hop-1 matmuls, both paths, split-K=4 each, 128^2 tiles (partials overwrite dead H1)
  k_mm2<<<dim3(8, 8, 8), b256, 0, stream>>>(A, D0, F0, A + NN,
                                            A + 2 * NN, D1, F1, A + 3 * NN, P);
  k_sumdeg2<<<dim3(1024, 2), b256, 0, stream>>>(P, D0, F0, D1, F1);

  // path1 hop-2 matmul, split-K=4
  k_mm4<<<dim3(8, 8, 4), b256, 0, stream>>>(BT, D1, F1, A + 4 * NN, Pa, Pb);
  k_sumdeg4<<<1024, b256, 0, stream>>>(Pa, Pb, D1, F1);

  // combine + final deg
  k_maxdeg<<<1024, b256, 0, stream>>>(M0, D0, F0, M1, D1, F1, AN, D2, F2);

  // GCN layers (An normalization fused)
  k_an_mm<64, true><<<256, dim3(64, 4), 0, stream>>>(AN, D2, F2, XW1, bias1, HB);
  k_mm_small<64, 32, false, false><<<128, dim3(32, 8), 0, stream>>>(HB, w2, nullptr, HW2);
  k_an_mm<32, false><<<128, dim3(32, 8), 0, stream>>>(AN, D2, F2, HW2, bias2, out);
}